// Round 9
// baseline (118.079 us; speedup 1.0000x reference)
//
#include <hip/hip_runtime.h>
#include <math.h>

#define NBINS 80
#define NVERT 128
#define NRH 5
#define NDEG 6           // Taylor terms d=0..5; remainder ~1e-5 (<< f16 eps)

#define PSTR 136         // halves per P/M row; cols 0..127 data, 128..135 pad
#define DSTR 80          // halves per desc row (per nt)
#define DI   1280        // halves per desc feature slab (desc = exactly 10240 B)

#define OFF_W 6800       // w[d][vert]: 6 x 128 f16 = 1536 B at [6800,8336)
#define SLICE  10240     // per-sample LDS slice; desc overlay [0,10240) after chain1
#define SPW    2         // samples per wave (R9: intra-wave sample pipelining)
#define WPB    4         // waves per WG
#define SPB    (SPW*WPB) // samples per WG = 8; LDS 8*10240 = 81920 B/WG
                         // -> 2 WGs/CU = 8 waves/CU, 16 samples resident,
                         // 2 waves/SIMD each carrying 2-sample ILP

#define NSET_C 48        // C-matrix frag sets: 16 nt x 3 ks
#define NSET_W 60        // W frag sets: 4 i x 5 tiles x 3 ks
#define WS_BYTES ((NSET_C + NSET_W) * 64 * 8 * 2)

// Same-wave LDS ordering fences (replace __syncthreads; R3 lesson):
#define LDS_ORDER() asm volatile("" ::: "memory")
#define LDS_DRAIN() asm volatile("s_waitcnt lgkmcnt(0)" ::: "memory")

typedef _Float16 half8 __attribute__((ext_vector_type(8)));
typedef float f32x4 __attribute__((ext_vector_type(4)));

// ---- prep: constant C-matrix frags + W frags in d_ws (unchanged, verified) ----
__global__ __launch_bounds__(64) void prep_frags(const float* __restrict__ Wc,
                                                 const float* __restrict__ sig_th,
                                                 _Float16* __restrict__ ws) {
    const int blk  = blockIdx.x;
    const int lane = threadIdx.x;
    constexpr float TWO_PI = 6.28318530717958647692f;
    constexpr float DLT    = TWO_PI / 16.0f;
    constexpr float LN2    = 0.69314718055994530942f;
    half8 h;
    if (blk < NSET_C) {
        constexpr float LOG2E = 1.44269504088896340736f;
        constexpr float EPSF  = 1e-5f;
        const float st = sig_th[0];
        const float Kt = -LOG2E / (st * st + EPSF);
        const int ks = blk % 3;
        const int nt = blk / 3;
        const int t  = lane & 15;
        const int q  = lane >> 4;
        #pragma unroll
        for (int j = 0; j < 8; ++j) {
            const int k = ks * 32 + q * 8 + j;     // 0..95
            const int a = k / NDEG;
            const int d = k % NDEG;
            const int m = ((a + nt) & 15) - t;
            const float s = fmaf((float)m, DLT, 0.5f * DLT);
            const float z = 2.0f * LN2 * Kt * s * (0.5f * DLT);
            float val = exp2f(Kt * s * s);
            for (int dd = 1; dd <= d; ++dd) val *= z / (float)dd;
            h[j] = (_Float16)val;
        }
    } else {
        const int e    = blk - NSET_C;
        const int ks   = e % 3;
        const int tile = (e / 3) % 5;
        const int i    = e / 15;
        const int cc   = tile * 16 + (lane & 15);
        const int bb0  = ks * 32 + (lane >> 4) * 8;
        #pragma unroll
        for (int j = 0; j < 8; ++j) {
            const int bb = bb0 + j;
            h[j] = (_Float16)((bb < NBINS) ? Wc[i * NBINS * NBINS + bb * NBINS + cc] : 0.0f);
        }
    }
    *(half8*)(ws + ((size_t)blk * 64 + lane) * 8) = h;
}

// R9: TWO SAMPLES PER WAVE, phase-fused. Every phase body processes both
// samples back-to-back so B's independent loads/VALU overlap A's MFMAs at
// the scheduler level (breaks the all-waves-in-the-same-phase convoy that
// pinned throughput at ~2.4us/sample across R2..R8 structures). Shared
// across the pair: chain2 C-frags and phase2 W-frags loaded ONCE. chain1 is
// branch-free fixed 4 chunks (beyond-nc bins/w are zeroed -> B self-masks).
// rcp Newton dropped (v_rcp ~2^-22 rel err << f16 2^-11). ZERO barriers;
// same-wave DS ordering via LDS_ORDER/LDS_DRAIN (R3 lesson).
template <int USEWS>
__global__ __launch_bounds__(256, 2) void masif_geo_conv(
    const float* __restrict__ rho_c,
    const float* __restrict__ th_c,
    const float* __restrict__ feat_g,
    const float* __restrict__ mask_g,
    const float* __restrict__ mu_rho,
    const float* __restrict__ sig_rho,
    const float* __restrict__ mu_th,
    const float* __restrict__ sig_th,
    const float* __restrict__ Wc,
    const float* __restrict__ bcv,
    const _Float16* __restrict__ ws,
    const int nsamp,
    float* __restrict__ out)
{
    const int wave = threadIdx.x >> 6;
    const int lane = threadIdx.x & 63;
    const int na   = blockIdx.x * SPB + wave * SPW;  // sample A
    const int nb   = na + 1;                         // sample B

    __shared__ __align__(16) char s_raw[SPB * SLICE];

    if (na >= nsamp) return;                  // safe: no barriers anywhere
    const bool okB = (nb < nsamp);
    const int  nbC = okB ? nb : na;           // clamp for addressing only

    const int t  = lane & 15;
    const int kq = lane >> 4;

    char* baseA = s_raw + (wave * SPW + 0) * SLICE;
    char* baseB = s_raw + (wave * SPW + 1) * SLICE;
    _Float16* s_PMa = (_Float16*)baseA;
    _Float16* s_PMb = (_Float16*)baseB;
    _Float16* s_wa  = (_Float16*)(baseA + OFF_W);
    _Float16* s_wb  = (_Float16*)(baseB + OFF_W);
    _Float16* s_da  = (_Float16*)baseA;              // desc overlay (late)
    _Float16* s_db  = (_Float16*)baseB;

    constexpr float LOG2E   = 1.44269504088896340736f;
    constexpr float TWO_PI  = 6.28318530717958647692f;
    constexpr float DLT     = TWO_PI / 16.0f;
    constexpr float INV_DLT = 16.0f / TWO_PI;
    constexpr float EPSF    = 1e-5f;

    const float st = sig_th[0];
    const float Kt = -LOG2E / (st * st + EPSF);
    const float sr = sig_rho[0];
    const float Kr = -LOG2E / (sr * sr + EPSF);
    float mr[NRH];
    #pragma unroll
    for (int r = 0; r < NRH; ++r) mr[r] = mu_rho[r * 16];

    // ---- zero both slices [0, 8704 B) = 544 int4 (P + pads + w + slack:
    //      keeps beyond-nc bins/w and chain2's A1 rows 25..31 all zero) ----
    #pragma unroll
    for (int x = 0; x < 9; ++x) {
        const int idx = x * 64 + lane;
        if (idx < 544) {
            ((int4*)s_PMa)[idx] = make_int4(0, 0, 0, 0);
            ((int4*)s_PMb)[idx] = make_int4(0, 0, 0, 0);
        }
    }
    LDS_ORDER();                                  // [1] zero before compaction

    // ---- compaction fused: both samples per round; B's global latency
    //      hides under A's exp2/stores ----
    int ncA = 0, ncB = 0;
    #pragma unroll
    for (int h = 0; h < 2; ++h) {
        const int v = h * 64 + lane;
        const float  mvA = mask_g[na * NVERT + v];
        const float  thA = th_c[na * NVERT + v];
        const float  rhA = rho_c[na * NVERT + v];
        const float4 f4A = *(const float4*)&feat_g[(na * NVERT + v) * 4];
        const float  mvB = mask_g[nbC * NVERT + v];
        const float  thB = th_c[nbC * NVERT + v];
        const float  rhB = rho_c[nbC * NVERT + v];
        const float4 f4B = *(const float4*)&feat_g[(nbC * NVERT + v) * 4];

        // sample A
        {
            const bool act = (mvA != 0.0f);
            const unsigned long long bal = __ballot(act);
            if (act) {
                const int pos = ncA + (int)__popcll(bal & ((1ull << lane) - 1ull));
                int aa = (int)floorf(thA * INV_DLT);
                aa = aa > 15 ? 15 : (aa < 0 ? 0 : aa);
                const float rvp = thA - (float)aa * DLT - 0.5f * DLT;
                float R[NRH];
                #pragma unroll
                for (int r = 0; r < NRH; ++r) {
                    const float dr = rhA - mr[r];
                    R[r] = mvA * exp2f(Kr * dr * dr);
                }
                const float fv[4] = {f4A.x, f4A.y, f4A.z, f4A.w};
                #pragma unroll
                for (int f = 0; f < 4; ++f) {
                    #pragma unroll
                    for (int r = 0; r < 4; ++r)
                        s_PMa[(f * 4 + r) * PSTR + pos] = (_Float16)(fv[f] * R[r]);
                    s_PMa[(16 + f) * PSTR + pos] = (_Float16)(fv[f] * R[4]);
                }
                #pragma unroll
                for (int r = 0; r < NRH; ++r)
                    s_PMa[(20 + r) * PSTR + pos] = (_Float16)R[r];
                ((char*)s_PMa)[(16 + (pos >> 4)) * 2 * PSTR + 256 + (pos & 15)] = (char)aa;
                const float gth = exp2f(Kt * rvp * rvp);
                const float uu  = rvp * (2.0f * INV_DLT);
                float wacc = gth;
                #pragma unroll
                for (int d = 0; d < 6; ++d) {
                    s_wa[d * 128 + pos] = (_Float16)wacc;
                    wacc *= uu;
                }
            }
            ncA += (int)__popcll(bal);
        }
        // sample B
        {
            const bool act = (mvB != 0.0f);
            const unsigned long long bal = __ballot(act);
            if (act) {
                const int pos = ncB + (int)__popcll(bal & ((1ull << lane) - 1ull));
                int aa = (int)floorf(thB * INV_DLT);
                aa = aa > 15 ? 15 : (aa < 0 ? 0 : aa);
                const float rvp = thB - (float)aa * DLT - 0.5f * DLT;
                float R[NRH];
                #pragma unroll
                for (int r = 0; r < NRH; ++r) {
                    const float dr = rhB - mr[r];
                    R[r] = mvB * exp2f(Kr * dr * dr);
                }
                const float fv[4] = {f4B.x, f4B.y, f4B.z, f4B.w};
                #pragma unroll
                for (int f = 0; f < 4; ++f) {
                    #pragma unroll
                    for (int r = 0; r < 4; ++r)
                        s_PMb[(f * 4 + r) * PSTR + pos] = (_Float16)(fv[f] * R[r]);
                    s_PMb[(16 + f) * PSTR + pos] = (_Float16)(fv[f] * R[4]);
                }
                #pragma unroll
                for (int r = 0; r < NRH; ++r)
                    s_PMb[(20 + r) * PSTR + pos] = (_Float16)R[r];
                ((char*)s_PMb)[(16 + (pos >> 4)) * 2 * PSTR + 256 + (pos & 15)] = (char)aa;
                const float gth = exp2f(Kt * rvp * rvp);
                const float uu  = rvp * (2.0f * INV_DLT);
                float wacc = gth;
                #pragma unroll
                for (int d = 0; d < 6; ++d) {
                    s_wb[d * 128 + pos] = (_Float16)wacc;
                    wacc *= uu;
                }
            }
            ncB += (int)__popcll(bal);
        }
    }
    LDS_DRAIN();                                  // [2] P/w/bins complete

    // ---- chain 1 fused, branch-free fixed 4 chunks (beyond-nc -> zeros).
    //      B frags built in regs: b[j] = (bin==a_req) ? w[d][vert] : 0. ----
    f32x4 M0a[6], M1a[6], M0b[6], M1b[6];
    #pragma unroll
    for (int cb = 0; cb < 6; ++cb) {
        M0a[cb] = (f32x4){0.f, 0.f, 0.f, 0.f};
        M1a[cb] = (f32x4){0.f, 0.f, 0.f, 0.f};
        M0b[cb] = (f32x4){0.f, 0.f, 0.f, 0.f};
        M1b[cb] = (f32x4){0.f, 0.f, 0.f, 0.f};
    }
    int areq[6], woff[6];
    #pragma unroll
    for (int lct = 0; lct < 6; ++lct) {
        const int row = lct * 16 + t;
        areq[lct] = row / 6;
        woff[lct] = (row % 6) * 128 + kq * 8;
    }
    #pragma unroll 1
    for (int ch = 0; ch < NVERT / 32; ++ch) {
        const int co = ch * 32 + kq * 8;
        const half8 av0a = *(const half8*)(s_PMa + t * PSTR + co);
        const half8 av1a = *(const half8*)(s_PMa + (16 + t) * PSTR + co);
        const half8 av0b = *(const half8*)(s_PMb + t * PSTR + co);
        const half8 av1b = *(const half8*)(s_PMb + (16 + t) * PSTR + co);
        const int boff = (16 + ch * 2 + (kq >> 1)) * 2 * PSTR + 256 + (kq & 1) * 8;
        const unsigned long long abA = *(const unsigned long long*)((const char*)s_PMa + boff);
        const unsigned long long abB = *(const unsigned long long*)((const char*)s_PMb + boff);
        int ajA[8], ajB[8];
        #pragma unroll
        for (int j = 0; j < 8; ++j) {
            ajA[j] = (int)((abA >> (8 * j)) & 0xffull);
            ajB[j] = (int)((abB >> (8 * j)) & 0xffull);
        }
        #pragma unroll
        for (int lct = 0; lct < 6; ++lct) {
            const half8 wvA = *(const half8*)(s_wa + woff[lct] + ch * 32);
            const half8 wvB = *(const half8*)(s_wb + woff[lct] + ch * 32);
            half8 bA, bB;
            #pragma unroll
            for (int j = 0; j < 8; ++j) {
                bA[j] = (ajA[j] == areq[lct]) ? wvA[j] : (_Float16)0.0f;
                bB[j] = (ajB[j] == areq[lct]) ? wvB[j] : (_Float16)0.0f;
            }
            __builtin_amdgcn_s_setprio(1);
            M0a[lct] = __builtin_amdgcn_mfma_f32_16x16x32_f16(av0a, bA, M0a[lct], 0, 0, 0);
            M1a[lct] = __builtin_amdgcn_mfma_f32_16x16x32_f16(av1a, bA, M1a[lct], 0, 0, 0);
            M0b[lct] = __builtin_amdgcn_mfma_f32_16x16x32_f16(av0b, bB, M0b[lct], 0, 0, 0);
            M1b[lct] = __builtin_amdgcn_mfma_f32_16x16x32_f16(av1b, bB, M1b[lct], 0, 0, 0);
            __builtin_amdgcn_s_setprio(0);
        }
    }
    LDS_ORDER();                                  // chain1 reads before M overwrite

    // ---- M -> LDS f16 A-layout, both samples. D: col=t, row=kq*4+reg ----
    #pragma unroll
    for (int cb = 0; cb < 6; ++cb) {
        const int md = cb * 16 + t;
        #pragma unroll
        for (int reg = 0; reg < 4; ++reg) {
            const int lr = kq * 4 + reg;
            s_PMa[lr * PSTR + md] = (_Float16)M0a[cb][reg];
            s_PMb[lr * PSTR + md] = (_Float16)M0b[cb][reg];
            if (lr < 9) {
                s_PMa[(16 + lr) * PSTR + md] = (_Float16)M1a[cb][reg];
                s_PMb[(16 + lr) * PSTR + md] = (_Float16)M1b[cb][reg];
            }
        }
    }
    LDS_DRAIN();                                  // [3] M complete before A-frag reads

    // ---- chain2 A-frags -> regs, both samples (before desc overlay) ----
    half8 A0a[3], A1a[3], A0b[3], A1b[3];
    #pragma unroll
    for (int ks = 0; ks < 3; ++ks) {
        A0a[ks] = *(const half8*)(s_PMa + t * PSTR + ks * 32 + kq * 8);
        A1a[ks] = *(const half8*)(s_PMa + (16 + t) * PSTR + ks * 32 + kq * 8);
        A0b[ks] = *(const half8*)(s_PMb + t * PSTR + ks * 32 + kq * 8);
        A1b[ks] = *(const half8*)(s_PMb + (16 + t) * PSTR + ks * 32 + kq * 8);
    }
    LDS_ORDER();                                  // [4] A-frag reads before desc overlay

    // ---- chain 2 fused: C-frags loaded ONCE, used by both samples ----
    const half8* wsv = (const half8*)ws;
    #pragma unroll 1
    for (int g = 0; g < 4; ++g) {
        f32x4 C0a[4], C1a[4], C0b[4], C1b[4];
        #pragma unroll
        for (int j = 0; j < 4; ++j) {
            C0a[j] = (f32x4){0.f, 0.f, 0.f, 0.f};
            C1a[j] = (f32x4){0.f, 0.f, 0.f, 0.f};
            C0b[j] = (f32x4){0.f, 0.f, 0.f, 0.f};
            C1b[j] = (f32x4){0.f, 0.f, 0.f, 0.f};
        }
        #pragma unroll
        for (int j = 0; j < 4; ++j) {
            const int nt = g * 4 + j;
            half8 b0, b1, b2;
            if (USEWS) {
                b0 = wsv[(size_t)((nt * 3 + 0) * 64 + lane)];
                b1 = wsv[(size_t)((nt * 3 + 1) * 64 + lane)];
                b2 = wsv[(size_t)((nt * 3 + 2) * 64 + lane)];
            } else {
                #pragma unroll
                for (int ks = 0; ks < 3; ++ks) {
                    half8 bb;
                    #pragma unroll
                    for (int jj = 0; jj < 8; ++jj) {
                        const int k = ks * 32 + kq * 8 + jj;
                        const int a = k / NDEG, d = k % NDEG;
                        const int mm = ((a + nt) & 15) - t;
                        const float s = fmaf((float)mm, DLT, 0.5f * DLT);
                        const float z = 2.0f * 0.69314718055994530942f * Kt * s * (0.5f * DLT);
                        float val = exp2f(Kt * s * s);
                        for (int dd = 1; dd <= d; ++dd) val *= z / (float)dd;
                        bb[jj] = (_Float16)val;
                    }
                    if (ks == 0) b0 = bb; else if (ks == 1) b1 = bb; else b2 = bb;
                }
            }
            __builtin_amdgcn_s_setprio(1);
            C0a[j] = __builtin_amdgcn_mfma_f32_16x16x32_f16(A0a[0], b0, C0a[j], 0, 0, 0);
            C1a[j] = __builtin_amdgcn_mfma_f32_16x16x32_f16(A1a[0], b0, C1a[j], 0, 0, 0);
            C0b[j] = __builtin_amdgcn_mfma_f32_16x16x32_f16(A0b[0], b0, C0b[j], 0, 0, 0);
            C1b[j] = __builtin_amdgcn_mfma_f32_16x16x32_f16(A1b[0], b0, C1b[j], 0, 0, 0);
            C0a[j] = __builtin_amdgcn_mfma_f32_16x16x32_f16(A0a[1], b1, C0a[j], 0, 0, 0);
            C1a[j] = __builtin_amdgcn_mfma_f32_16x16x32_f16(A1a[1], b1, C1a[j], 0, 0, 0);
            C0b[j] = __builtin_amdgcn_mfma_f32_16x16x32_f16(A0b[1], b1, C0b[j], 0, 0, 0);
            C1b[j] = __builtin_amdgcn_mfma_f32_16x16x32_f16(A1b[1], b1, C1b[j], 0, 0, 0);
            C0a[j] = __builtin_amdgcn_mfma_f32_16x16x32_f16(A0a[2], b2, C0a[j], 0, 0, 0);
            C1a[j] = __builtin_amdgcn_mfma_f32_16x16x32_f16(A1a[2], b2, C1a[j], 0, 0, 0);
            C0b[j] = __builtin_amdgcn_mfma_f32_16x16x32_f16(A0b[2], b2, C0b[j], 0, 0, 0);
            C1b[j] = __builtin_amdgcn_mfma_f32_16x16x32_f16(A1b[2], b2, C1b[j], 0, 0, 0);
            __builtin_amdgcn_s_setprio(0);
        }
        // fused epilogue (rcp WITHOUT Newton: f16-bound output), both samples
        #pragma unroll
        for (int j = 0; j < 4; ++j) {
            const int nt = g * 4 + j;
            float denA[5], invA[5], denB[5], invB[5];
            #pragma unroll
            for (int r = 0; r < 4; ++r) {
                denA[r] = __shfl(C1a[j][r], 16 + t);
                denB[r] = __shfl(C1b[j][r], 16 + t);
            }
            denA[4] = __shfl(C1a[j][0], 32 + t);
            denB[4] = __shfl(C1b[j][0], 32 + t);
            #pragma unroll
            for (int r = 0; r < NRH; ++r) {
                invA[r] = __builtin_amdgcn_rcpf(denA[r] + EPSF);
                invB[r] = __builtin_amdgcn_rcpf(denB[r] + EPSF);
            }
            #pragma unroll
            for (int reg = 0; reg < 4; ++reg) {
                s_da[kq * DI + nt * DSTR + reg * 16 + t] = (_Float16)(C0a[j][reg] * invA[reg]);
                s_db[kq * DI + nt * DSTR + reg * 16 + t] = (_Float16)(C0b[j][reg] * invB[reg]);
            }
            if (kq == 0) {
                #pragma unroll
                for (int reg = 0; reg < 4; ++reg) {
                    s_da[reg * DI + nt * DSTR + 64 + t] = (_Float16)(C1a[j][reg] * invA[4]);
                    s_db[reg * DI + nt * DSTR + 64 + t] = (_Float16)(C1b[j][reg] * invB[4]);
                }
            }
        }
    }
    LDS_DRAIN();                                  // [5] desc complete before phase2 reads

    // ---- phase 2 fused: W-frags loaded ONCE, used by both samples ----
    #pragma unroll 1
    for (int i = 0; i < 4; ++i) {
        f32x4 Ca[5], Cb[5];
        #pragma unroll
        for (int tl = 0; tl < 5; ++tl) {
            Ca[tl] = (f32x4){0.f, 0.f, 0.f, 0.f};
            Cb[tl] = (f32x4){0.f, 0.f, 0.f, 0.f};
        }
        #pragma unroll
        for (int ks = 0; ks < 3; ++ks) {
            const half8 aA = *(const half8*)(s_da + i * DI + t * DSTR + ks * 32 + kq * 8);
            const half8 aB = *(const half8*)(s_db + i * DI + t * DSTR + ks * 32 + kq * 8);
            half8 b[5];
            #pragma unroll
            for (int tl = 0; tl < 5; ++tl) {
                if (USEWS) {
                    b[tl] = wsv[(size_t)((NSET_C + (i * 5 + tl) * 3 + ks) * 64 + lane)];
                } else {
                    const int cc  = tl * 16 + t;
                    const int bb0 = ks * 32 + kq * 8;
                    #pragma unroll
                    for (int j = 0; j < 8; ++j) {
                        const int bb = bb0 + j;
                        b[tl][j] = (_Float16)((bb < NBINS) ? Wc[i * NBINS * NBINS + bb * NBINS + cc] : 0.0f);
                    }
                }
            }
            __builtin_amdgcn_s_setprio(1);
            #pragma unroll
            for (int tl = 0; tl < 5; ++tl) {
                Ca[tl] = __builtin_amdgcn_mfma_f32_16x16x32_f16(aA, b[tl], Ca[tl], 0, 0, 0);
                Cb[tl] = __builtin_amdgcn_mfma_f32_16x16x32_f16(aB, b[tl], Cb[tl], 0, 0, 0);
            }
            __builtin_amdgcn_s_setprio(0);
        }
        #pragma unroll
        for (int tl = 0; tl < 5; ++tl) {
            float mxA = fmaxf(fmaxf(Ca[tl][0], Ca[tl][1]), fmaxf(Ca[tl][2], Ca[tl][3]));
            mxA = fmaxf(mxA, __shfl_xor(mxA, 16));
            mxA = fmaxf(mxA, __shfl_xor(mxA, 32));
            float mxB = fmaxf(fmaxf(Cb[tl][0], Cb[tl][1]), fmaxf(Cb[tl][2], Cb[tl][3]));
            mxB = fmaxf(mxB, __shfl_xor(mxB, 16));
            mxB = fmaxf(mxB, __shfl_xor(mxB, 32));
            if (lane < 16) {
                const int cc = tl * 16 + lane;
                const float bc = bcv[i * NBINS + cc];
                out[(size_t)na * 320 + i * NBINS + cc] = fmaxf(mxA + bc, 0.0f);
                if (okB)
                    out[(size_t)nb * 320 + i * NBINS + cc] = fmaxf(mxB + bc, 0.0f);
            }
        }
    }
}

extern "C" void kernel_launch(void* const* d_in, const int* in_sizes, int n_in,
                              void* d_out, int out_size, void* d_ws, size_t ws_size,
                              hipStream_t stream) {
    const float* rho   = (const float*)d_in[0];
    const float* theta = (const float*)d_in[1];
    const float* feat  = (const float*)d_in[2];
    const float* mask  = (const float*)d_in[3];
    const float* mu_r  = (const float*)d_in[4];
    const float* sg_r  = (const float*)d_in[5];
    const float* mu_t  = (const float*)d_in[6];
    const float* sg_t  = (const float*)d_in[7];
    const float* W     = (const float*)d_in[8];
    const float* bconv = (const float*)d_in[9];
    float* outp = (float*)d_out;

    const int nsamp = in_sizes[0] / NVERT;
    const int ngrid = (nsamp + SPB - 1) / SPB;    // 8 samples per WG
    const int useWs = (ws_size >= (size_t)WS_BYTES) ? 1 : 0;
    _Float16* wsh = (_Float16*)d_ws;

    if (useWs) {
        prep_frags<<<NSET_C + NSET_W, 64, 0, stream>>>(W, sg_t, wsh);
        masif_geo_conv<1><<<ngrid, 64 * WPB, 0, stream>>>(
            rho, theta, feat, mask, mu_r, sg_r, mu_t, sg_t, W, bconv,
            wsh, nsamp, outp);
    } else {
        masif_geo_conv<0><<<ngrid, 64 * WPB, 0, stream>>>(
            rho, theta, feat, mask, mu_r, sg_r, mu_t, sg_t, W, bconv,
            wsh, nsamp, outp);
    }
}

// Round 10
// 108.574 us; speedup vs baseline: 1.0875x; 1.0875x over previous
//
#include <hip/hip_runtime.h>
#include <math.h>

#define NBINS 80
#define NVERT 128
#define NRH 5
#define NDEG 6           // Taylor terms d=0..5; remainder ~1e-5 (<< f16 eps)

#define PSTR 136         // halves per P/M row; cols 0..127 data, 128..135 pad
#define VSTR 32          // halves per VT row
#define DSTR 80          // halves per desc row (per nt)
#define DI   1280        // halves per desc feature slab (desc = exactly 10240 B)

#define OFF_VT 6800      // P/M: 25*136*2 = 6800 B at [0,6800)
#define VTSZ   3072      // VT: 48 rows x 32 halves (one a-half at a time)
#define OFF_GM 9872      // gm f16 x 128 = 256 B at [9872,10128)
#define SLICE  10240     // per-sample LDS slice; desc overlay [0,10240) after chain1
#define WPB    4         // samples (waves) per WG; 4*10240 = 40960 B/WG
                         // -> 4 WGs/CU = 16 waves/CU (LDS-capped maximum)

#define NSET_C 48        // C-matrix frag sets: 16 nt x 3 ks
#define NSET_W 60        // W frag sets: 4 i x 5 tiles x 3 ks
#define WS_BYTES ((NSET_C + NSET_W) * 64 * 8 * 2)

// Same-wave LDS ordering fences (replace __syncthreads; R3 lesson):
#define LDS_ORDER() asm volatile("" ::: "memory")
#define LDS_DRAIN() asm volatile("s_waitcnt lgkmcnt(0)" ::: "memory")

typedef _Float16 half8 __attribute__((ext_vector_type(8)));
typedef float f32x4 __attribute__((ext_vector_type(4)));

// ---- prep: constant C-matrix frags + W frags in d_ws (unchanged, verified) ----
__global__ __launch_bounds__(64) void prep_frags(const float* __restrict__ Wc,
                                                 const float* __restrict__ sig_th,
                                                 _Float16* __restrict__ ws) {
    const int blk  = blockIdx.x;
    const int lane = threadIdx.x;
    constexpr float TWO_PI = 6.28318530717958647692f;
    constexpr float DLT    = TWO_PI / 16.0f;
    constexpr float LN2    = 0.69314718055994530942f;
    half8 h;
    if (blk < NSET_C) {
        constexpr float LOG2E = 1.44269504088896340736f;
        constexpr float EPSF  = 1e-5f;
        const float st = sig_th[0];
        const float Kt = -LOG2E / (st * st + EPSF);
        const int ks = blk % 3;
        const int nt = blk / 3;
        const int t  = lane & 15;
        const int q  = lane >> 4;
        #pragma unroll
        for (int j = 0; j < 8; ++j) {
            const int k = ks * 32 + q * 8 + j;     // 0..95
            const int a = k / NDEG;
            const int d = k % NDEG;
            const int m = ((a + nt) & 15) - t;
            const float s = fmaf((float)m, DLT, 0.5f * DLT);
            const float z = 2.0f * LN2 * Kt * s * (0.5f * DLT);
            float val = exp2f(Kt * s * s);
            for (int dd = 1; dd <= d; ++dd) val *= z / (float)dd;
            h[j] = (_Float16)val;
        }
    } else {
        const int e    = blk - NSET_C;
        const int ks   = e % 3;
        const int tile = (e / 3) % 5;
        const int i    = e / 15;
        const int cc   = tile * 16 + (lane & 15);
        const int bb0  = ks * 32 + (lane >> 4) * 8;
        #pragma unroll
        for (int j = 0; j < 8; ++j) {
            const int bb = bb0 + j;
            h[j] = (_Float16)((bb < NBINS) ? Wc[i * NBINS * NBINS + bb * NBINS + cc] : 0.0f);
        }
    }
    *(half8*)(ws + ((size_t)blk * 64 + lane) * 8) = h;
}

// WAVE-PER-SAMPLE, 4 samples per 256-thread WG (R7 structure = session best;
// R10 micro-opts). ZERO barriers; same-wave DS ordering via LDS_ORDER/
// LDS_DRAIN (R3 lesson). R10 changes vs R7: (1) chain2 batches all 12 ws
// B-frags of a g into registers BEFORE the MFMA cluster (one ~250cyc L2
// exposure per g instead of 4); (2) phase2 batches all 15 W-frags per i
// likewise; both with unroll 1 to stay <=128 VGPR @ 4 waves/SIMD;
// (3) rcp Newton dropped (R9 verified absmax unchanged -- f16-bound output).
template <int USEWS>
__global__ __launch_bounds__(256, 4) void masif_geo_conv(
    const float* __restrict__ rho_c,
    const float* __restrict__ th_c,
    const float* __restrict__ feat_g,
    const float* __restrict__ mask_g,
    const float* __restrict__ mu_rho,
    const float* __restrict__ sig_rho,
    const float* __restrict__ mu_th,
    const float* __restrict__ sig_th,
    const float* __restrict__ Wc,
    const float* __restrict__ bcv,
    const _Float16* __restrict__ ws,
    const int nsamp,
    float* __restrict__ out)
{
    const int wave = threadIdx.x >> 6;
    const int lane = threadIdx.x & 63;
    const int n    = blockIdx.x * WPB + wave; // one sample per wave

    __shared__ __align__(16) char s_raw[WPB * SLICE];

    if (n >= nsamp) return;                   // safe: no barriers anywhere

    const int t  = lane & 15;
    const int kq = lane >> 6 ? 0 : (lane >> 4);   // kq = lane>>4 (0..3)

    char* s_base = s_raw + wave * SLICE;      // private per-wave slice
    _Float16* s_PM = (_Float16*)(s_base);                 // P, then M
    _Float16* s_vt = (_Float16*)(s_base + OFF_VT);        // VT (one col-half)
    _Float16* s_gm = (_Float16*)(s_base + OFF_GM);
    _Float16* s_d  = (_Float16*)(s_base);                 // desc overlay (late)

    constexpr float LOG2E   = 1.44269504088896340736f;
    constexpr float TWO_PI  = 6.28318530717958647692f;
    constexpr float DLT     = TWO_PI / 16.0f;
    constexpr float INV_DLT = 16.0f / TWO_PI;
    constexpr float EPSF    = 1e-5f;

    const float st = sig_th[0];
    const float Kt = -LOG2E / (st * st + EPSF);
    const float sr = sig_rho[0];
    const float Kr = -LOG2E / (sr * sr + EPSF);
    float mr[NRH];
    #pragma unroll
    for (int r = 0; r < NRH; ++r) mr[r] = mu_rho[r * 16];

    // ---- zero P incl. pads (425 int4, 64 lanes -> 7 rounds) ----
    #pragma unroll
    for (int x = 0; x < 7; ++x) {
        const int idx = x * 64 + lane;
        if (idx < 425) ((int4*)s_PM)[idx] = make_int4(0, 0, 0, 0);
    }
    LDS_ORDER();                                  // [1] zero before compaction

    // ---- compaction: 128 verts in 2 rounds of 64, wave-local ballot ----
    int nc = 0;
    #pragma unroll
    for (int h = 0; h < 2; ++h) {
        const int v     = h * 64 + lane;
        const float mv   = mask_g[n * NVERT + v];
        const float thv  = th_c[n * NVERT + v];
        const float rhov = rho_c[n * NVERT + v];
        const float4 f4  = *(const float4*)&feat_g[(n * NVERT + v) * 4];
        const bool act = (mv != 0.0f);
        const unsigned long long bal = __ballot(act);
        if (act) {
            const int pos = nc + (int)__popcll(bal & ((1ull << lane) - 1ull));
            int aa = (int)floorf(thv * INV_DLT);
            aa = aa > 15 ? 15 : (aa < 0 ? 0 : aa);
            const float rvp = thv - (float)aa * DLT - 0.5f * DLT;   // [-DLT/2, DLT/2)
            float R[NRH];
            #pragma unroll
            for (int r = 0; r < NRH; ++r) {
                const float dr = rhov - mr[r];
                R[r] = mv * exp2f(Kr * dr * dr);
            }
            const float fv[4] = {f4.x, f4.y, f4.z, f4.w};
            #pragma unroll
            for (int f = 0; f < 4; ++f) {
                #pragma unroll
                for (int r = 0; r < 4; ++r)
                    s_PM[(f * 4 + r) * PSTR + pos] = (_Float16)(fv[f] * R[r]);
                s_PM[(16 + f) * PSTR + pos] = (_Float16)(fv[f] * R[4]);
            }
            #pragma unroll
            for (int r = 0; r < NRH; ++r)
                s_PM[(20 + r) * PSTR + pos] = (_Float16)R[r];
            s_PM[(pos >> 3) * PSTR + 128 + (pos & 7)] = (_Float16)(rvp * (2.0f * INV_DLT));
            ((char*)s_PM)[(16 + (pos >> 4)) * 2 * PSTR + 256 + (pos & 15)] = (char)aa;
            s_gm[pos] = (_Float16)exp2f(Kt * rvp * rvp);
        }
        nc += (int)__popcll(bal);
    }
    LDS_DRAIN();                                  // [2] P/gm/tails complete

    // ---- chain 1: whole M (both tiles), software-pipelined chunks (R7).
    //      Preload chunk 0's A-frags + vert data; inside chunk ch, prefetch
    //      chunk ch+1 (P region immutable during chain1 -> safe to hoist). ----
    f32x4 M0[6], M1[6];
    #pragma unroll
    for (int cb = 0; cb < 6; ++cb) {
        M0[cb] = (f32x4){0.f, 0.f, 0.f, 0.f};
        M1[cb] = (f32x4){0.f, 0.f, 0.f, 0.f};
    }
    const int nch = (nc + 31) >> 5;
    const int cl = lane >> 1;
    const int dh = (lane & 1) * 3;
    // preload chunk 0
    half8 av0 = *(const half8*)(s_PM + t * PSTR + kq * 8);
    half8 av1 = *(const half8*)(s_PM + (16 + t) * PSTR + kq * 8);
    int   va  = (int)((char*)s_PM)[(16 + (cl >> 4)) * 2 * PSTR + 256 + (cl & 15)];
    float vu  = (float)s_PM[(cl >> 3) * PSTR + 128 + (cl & 7)];
    float vg  = (float)s_gm[cl];
    #pragma unroll 1
    for (int ch = 0; ch < nch; ++ch) {
        const bool valid = (ch * 32 + cl) < nc;
        float p0, p1, p2;
        if (dh == 0) { p0 = 1.0f; p1 = vu; p2 = vu * vu; }
        else { const float u2 = vu * vu; p0 = u2 * vu; p1 = u2 * u2; p2 = p0 * u2; }
        const _Float16 w0 = (_Float16)(vg * p0);
        const _Float16 w1 = (_Float16)(vg * p1);
        const _Float16 w2 = (_Float16)(vg * p2);
        const int ah  = va >> 3;                 // col-half this vert belongs to
        const int bi0 = ((va & 7) * NDEG + dh) * VSTR + cl;
        // prefetch chunk ch+1 (clamped; garbage beyond nc is masked next iter)
        const int chn = (ch + 1 < nch) ? (ch + 1) : ch;
        const int cgn = chn * 32 + cl;
        const half8 av0n = *(const half8*)(s_PM + t * PSTR + chn * 32 + kq * 8);
        const half8 av1n = *(const half8*)(s_PM + (16 + t) * PSTR + chn * 32 + kq * 8);
        const int   van  = (int)((char*)s_PM)[(16 + (cgn >> 4)) * 2 * PSTR + 256 + (cgn & 15)];
        const float vun  = (float)s_PM[(cgn >> 3) * PSTR + 128 + (cgn & 7)];
        const float vgn  = (float)s_gm[cgn];
        #pragma unroll
        for (int chalf = 0; chalf < 2; ++chalf) {
            LDS_ORDER();                  // prev col-half's VT reads before re-zero
            #pragma unroll
            for (int x = 0; x < 3; ++x)
                ((int4*)s_vt)[x * 64 + lane] = make_int4(0, 0, 0, 0);
            LDS_ORDER();                  // zero before scatter-build
            if (valid && ah == chalf) {
                s_vt[bi0]            = w0;
                s_vt[bi0 + VSTR]     = w1;
                s_vt[bi0 + 2 * VSTR] = w2;
            }
            LDS_ORDER();                  // build before fragment reads
            // tile1 t>8 reads rows 25..31 (in-slice garbage -> unread M rows)
            #pragma unroll
            for (int lct = 0; lct < 3; ++lct) {
                const half8 b = *(const half8*)(s_vt + (lct * 16 + t) * VSTR + kq * 8);
                __builtin_amdgcn_s_setprio(1);
                M0[chalf * 3 + lct] = __builtin_amdgcn_mfma_f32_16x16x32_f16(av0, b, M0[chalf * 3 + lct], 0, 0, 0);
                M1[chalf * 3 + lct] = __builtin_amdgcn_mfma_f32_16x16x32_f16(av1, b, M1[chalf * 3 + lct], 0, 0, 0);
                __builtin_amdgcn_s_setprio(0);
            }
        }
        av0 = av0n; av1 = av1n; va = van; vu = vun; vg = vgn;
    }
    LDS_ORDER();                                  // chain1 reads before M overwrite

    // ---- M (both tiles) -> LDS f16 A-layout. D: col=t, row=kq*4+reg ----
    #pragma unroll
    for (int cb = 0; cb < 6; ++cb) {
        const int md = cb * 16 + t;
        #pragma unroll
        for (int reg = 0; reg < 4; ++reg) {
            const int lr = kq * 4 + reg;
            s_PM[lr * PSTR + md] = (_Float16)M0[cb][reg];
            if (lr < 9)
                s_PM[(16 + lr) * PSTR + md] = (_Float16)M1[cb][reg];
        }
    }
    LDS_DRAIN();                                  // [3] M complete before A-frag reads

    // ---- chain2 A-frags -> regs (before desc overlays P/M) ----
    half8 A0[3], A1[3];
    #pragma unroll
    for (int ks = 0; ks < 3; ++ks) {
        A0[ks] = *(const half8*)(s_PM + t * PSTR + ks * 32 + kq * 8);
        A1[ks] = *(const half8*)(s_PM + (16 + t) * PSTR + ks * 32 + kq * 8);
    }
    LDS_ORDER();                                  // [4] A-frag reads before desc overlay

    // ---- chain 2: per g, BATCH all 12 B-frags -> regs, then MFMA cluster,
    //      then fused epilogue. unroll 1 keeps VGPR <= 128. ----
    const half8* wsv = (const half8*)ws;
    #pragma unroll 1
    for (int g = 0; g < 4; ++g) {
        half8 B0[4], B1[4], B2[4];
        #pragma unroll
        for (int j = 0; j < 4; ++j) {
            const int nt = g * 4 + j;
            if (USEWS) {
                B0[j] = wsv[(size_t)((nt * 3 + 0) * 64 + lane)];
                B1[j] = wsv[(size_t)((nt * 3 + 1) * 64 + lane)];
                B2[j] = wsv[(size_t)((nt * 3 + 2) * 64 + lane)];
            } else {
                #pragma unroll
                for (int ks = 0; ks < 3; ++ks) {
                    half8 bb;
                    #pragma unroll
                    for (int jj = 0; jj < 8; ++jj) {
                        const int k = ks * 32 + kq * 8 + jj;
                        const int a = k / NDEG, d = k % NDEG;
                        const int mm = ((a + nt) & 15) - t;
                        const float s = fmaf((float)mm, DLT, 0.5f * DLT);
                        const float z = 2.0f * 0.69314718055994530942f * Kt * s * (0.5f * DLT);
                        float val = exp2f(Kt * s * s);
                        for (int dd = 1; dd <= d; ++dd) val *= z / (float)dd;
                        bb[jj] = (_Float16)val;
                    }
                    if (ks == 0) B0[j] = bb; else if (ks == 1) B1[j] = bb; else B2[j] = bb;
                }
            }
        }
        f32x4 C0g[4], C1g[4];
        #pragma unroll
        for (int j = 0; j < 4; ++j) {
            C0g[j] = (f32x4){0.f, 0.f, 0.f, 0.f};
            C1g[j] = (f32x4){0.f, 0.f, 0.f, 0.f};
        }
        #pragma unroll
        for (int j = 0; j < 4; ++j) {
            __builtin_amdgcn_s_setprio(1);
            C0g[j] = __builtin_amdgcn_mfma_f32_16x16x32_f16(A0[0], B0[j], C0g[j], 0, 0, 0);
            C1g[j] = __builtin_amdgcn_mfma_f32_16x16x32_f16(A1[0], B0[j], C1g[j], 0, 0, 0);
            C0g[j] = __builtin_amdgcn_mfma_f32_16x16x32_f16(A0[1], B1[j], C0g[j], 0, 0, 0);
            C1g[j] = __builtin_amdgcn_mfma_f32_16x16x32_f16(A1[1], B1[j], C1g[j], 0, 0, 0);
            C0g[j] = __builtin_amdgcn_mfma_f32_16x16x32_f16(A0[2], B2[j], C0g[j], 0, 0, 0);
            C1g[j] = __builtin_amdgcn_mfma_f32_16x16x32_f16(A1[2], B2[j], C1g[j], 0, 0, 0);
            __builtin_amdgcn_s_setprio(0);
        }
        // fused epilogue: desc = num/(den+eps) -> s_d[i][nt][bb]
        // rcp WITHOUT Newton (f16-bound output; R9-verified)
        #pragma unroll
        for (int j = 0; j < 4; ++j) {
            const int nt = g * 4 + j;
            float den[5], inv[5];
            #pragma unroll
            for (int r = 0; r < 4; ++r) den[r] = __shfl(C1g[j][r], 16 + t);
            den[4] = __shfl(C1g[j][0], 32 + t);
            #pragma unroll
            for (int r = 0; r < NRH; ++r)
                inv[r] = __builtin_amdgcn_rcpf(den[r] + EPSF);
            #pragma unroll
            for (int reg = 0; reg < 4; ++reg)
                s_d[kq * DI + nt * DSTR + reg * 16 + t] =
                    (_Float16)(C0g[j][reg] * inv[reg]);
            if (kq == 0) {
                #pragma unroll
                for (int reg = 0; reg < 4; ++reg)
                    s_d[reg * DI + nt * DSTR + 64 + t] =
                        (_Float16)(C1g[j][reg] * inv[4]);
            }
        }
    }
    LDS_DRAIN();                                  // [5] desc complete before phase2 reads

    // ---- phase 2: per i, BATCH 3 desc A-frags + all 15 W-frags, then
    //      MFMA cluster. unroll 1 keeps VGPR <= 128. ----
    #pragma unroll 1
    for (int i = 0; i < 4; ++i) {
        half8 a[3];
        #pragma unroll
        for (int ks = 0; ks < 3; ++ks)
            a[ks] = *(const half8*)(s_d + i * DI + t * DSTR + ks * 32 + kq * 8);
        half8 b[15];
        #pragma unroll
        for (int ks = 0; ks < 3; ++ks) {
            #pragma unroll
            for (int tl = 0; tl < 5; ++tl) {
                if (USEWS) {
                    b[ks * 5 + tl] = wsv[(size_t)((NSET_C + (i * 5 + tl) * 3 + ks) * 64 + lane)];
                } else {
                    const int cc  = tl * 16 + t;
                    const int bb0 = ks * 32 + kq * 8;
                    #pragma unroll
                    for (int j = 0; j < 8; ++j) {
                        const int bb = bb0 + j;
                        b[ks * 5 + tl][j] = (_Float16)((bb < NBINS) ? Wc[i * NBINS * NBINS + bb * NBINS + cc] : 0.0f);
                    }
                }
            }
        }
        f32x4 Cc[5];
        #pragma unroll
        for (int tl = 0; tl < 5; ++tl) Cc[tl] = (f32x4){0.f, 0.f, 0.f, 0.f};
        __builtin_amdgcn_s_setprio(1);
        #pragma unroll
        for (int ks = 0; ks < 3; ++ks) {
            #pragma unroll
            for (int tl = 0; tl < 5; ++tl)
                Cc[tl] = __builtin_amdgcn_mfma_f32_16x16x32_f16(a[ks], b[ks * 5 + tl], Cc[tl], 0, 0, 0);
        }
        __builtin_amdgcn_s_setprio(0);
        #pragma unroll
        for (int tl = 0; tl < 5; ++tl) {
            float mx = fmaxf(fmaxf(Cc[tl][0], Cc[tl][1]), fmaxf(Cc[tl][2], Cc[tl][3]));
            mx = fmaxf(mx, __shfl_xor(mx, 16));
            mx = fmaxf(mx, __shfl_xor(mx, 32));
            if (lane < 16) {
                const int cc = tl * 16 + lane;
                out[(size_t)n * 320 + i * NBINS + cc] =
                    fmaxf(mx + bcv[i * NBINS + cc], 0.0f);
            }
        }
    }
}

extern "C" void kernel_launch(void* const* d_in, const int* in_sizes, int n_in,
                              void* d_out, int out_size, void* d_ws, size_t ws_size,
                              hipStream_t stream) {
    const float* rho   = (const float*)d_in[0];
    const float* theta = (const float*)d_in[1];
    const float* feat  = (const float*)d_in[2];
    const float* mask  = (const float*)d_in[3];
    const float* mu_r  = (const float*)d_in[4];
    const float* sg_r  = (const float*)d_in[5];
    const float* mu_t  = (const float*)d_in[6];
    const float* sg_t  = (const float*)d_in[7];
    const float* W     = (const float*)d_in[8];
    const float* bconv = (const float*)d_in[9];
    float* outp = (float*)d_out;

    const int nsamp = in_sizes[0] / NVERT;
    const int ngrid = (nsamp + WPB - 1) / WPB;    // 4 samples per WG
    const int useWs = (ws_size >= (size_t)WS_BYTES) ? 1 : 0;
    _Float16* wsh = (_Float16*)d_ws;

    if (useWs) {
        prep_frags<<<NSET_C + NSET_W, 64, 0, stream>>>(W, sg_t, wsh);
        masif_geo_conv<1><<<ngrid, 64 * WPB, 0, stream>>>(
            rho, theta, feat, mask, mu_r, sg_r, mu_t, sg_t, W, bconv,
            wsh, nsamp, outp);
    } else {
        masif_geo_conv<0><<<ngrid, 64 * WPB, 0, stream>>>(
            rho, theta, feat, mask, mu_r, sg_r, mu_t, sg_t, W, bconv,
            wsh, nsamp, outp);
    }
}

// Round 12
// 108.087 us; speedup vs baseline: 1.0924x; 1.0045x over previous
//
#include <hip/hip_runtime.h>
#include <math.h>

#define NBINS 80
#define NVERT 128
#define NRH 5
#define NDEG 6           // Taylor terms d=0..5; remainder ~1e-5 (<< f16 eps)

#define PSTR 136         // halves per P/M row; cols 0..127 data, 128..135 pad
#define VSTR 32          // halves per VT row
#define DSTR 80          // halves per desc row (per nt)
#define DI   1280        // halves per desc feature slab (desc = exactly 10240 B)

#define OFF_VT 6800      // P/M: 25*136*2 = 6800 B at [0,6800)
#define VTSZ   3072      // VT: 48 rows x 32 halves (one a-half at a time)
#define OFF_GM 9872      // gm f16 x 128 = 256 B at [9872,10128)
#define SLICE  10240     // per-sample LDS slice; desc overlay [0,10240) after chain1
#define WPB    4         // samples (waves) per WG; 4*10240 = 40960 B/WG
                         // -> 4 WGs/CU = 16 waves/CU (LDS-capped maximum:
                         // desc 10240 B/sample is irreducible)

#define NSET_C 48        // C-matrix frag sets: 16 nt x 3 ks
#define NSET_W 60        // W frag sets: 4 i x 5 tiles x 3 ks
#define WS_BYTES ((NSET_C + NSET_W) * 64 * 8 * 2)

// Same-wave LDS ordering fences (replace __syncthreads; R3 lesson):
#define LDS_ORDER() asm volatile("" ::: "memory")
#define LDS_DRAIN() asm volatile("s_waitcnt lgkmcnt(0)" ::: "memory")

typedef _Float16 half8 __attribute__((ext_vector_type(8)));
typedef float f32x4 __attribute__((ext_vector_type(4)));

// ---- prep: constant C-matrix frags + W frags in d_ws (unchanged, verified) ----
__global__ __launch_bounds__(64) void prep_frags(const float* __restrict__ Wc,
                                                 const float* __restrict__ sig_th,
                                                 _Float16* __restrict__ ws) {
    const int blk  = blockIdx.x;
    const int lane = threadIdx.x;
    constexpr float TWO_PI = 6.28318530717958647692f;
    constexpr float DLT    = TWO_PI / 16.0f;
    constexpr float LN2    = 0.69314718055994530942f;
    half8 h;
    if (blk < NSET_C) {
        constexpr float LOG2E = 1.44269504088896340736f;
        constexpr float EPSF  = 1e-5f;
        const float st = sig_th[0];
        const float Kt = -LOG2E / (st * st + EPSF);
        const int ks = blk % 3;
        const int nt = blk / 3;
        const int t  = lane & 15;
        const int q  = lane >> 4;
        #pragma unroll
        for (int j = 0; j < 8; ++j) {
            const int k = ks * 32 + q * 8 + j;     // 0..95
            const int a = k / NDEG;
            const int d = k % NDEG;
            const int m = ((a + nt) & 15) - t;
            const float s = fmaf((float)m, DLT, 0.5f * DLT);
            const float z = 2.0f * LN2 * Kt * s * (0.5f * DLT);
            float val = exp2f(Kt * s * s);
            for (int dd = 1; dd <= d; ++dd) val *= z / (float)dd;
            h[j] = (_Float16)val;
        }
    } else {
        const int e    = blk - NSET_C;
        const int ks   = e % 3;
        const int tile = (e / 3) % 5;
        const int i    = e / 15;
        const int cc   = tile * 16 + (lane & 15);
        const int bb0  = ks * 32 + (lane >> 4) * 8;
        #pragma unroll
        for (int j = 0; j < 8; ++j) {
            const int bb = bb0 + j;
            h[j] = (_Float16)((bb < NBINS) ? Wc[i * NBINS * NBINS + bb * NBINS + cc] : 0.0f);
        }
    }
    *(half8*)(ws + ((size_t)blk * 64 + lane) * 8) = h;
}

// WAVE-PER-SAMPLE, 4 samples per 256-thread WG (R10 base = session best;
// R11 DS cuts). ZERO barriers; same-wave DS ordering via LDS_ORDER/LDS_DRAIN
// (R3 lesson). R11 changes vs R10: (1) chain2 epilogue den broadcast packs
// den[0..3] into two f16 pairs -> 3 bpermutes per (g,j) instead of 5, all
// 12 per g issued as one batch (one DS-latency exposure, the R10 trick
// applied to shfl); den f16 rounding adds <=2^-11 rel to desc (f16-bound
// anyway). (2) compaction hoists both rounds' global loads up front.
template <int USEWS>
__global__ __launch_bounds__(256, 4) void masif_geo_conv(
    const float* __restrict__ rho_c,
    const float* __restrict__ th_c,
    const float* __restrict__ feat_g,
    const float* __restrict__ mask_g,
    const float* __restrict__ mu_rho,
    const float* __restrict__ sig_rho,
    const float* __restrict__ mu_th,
    const float* __restrict__ sig_th,
    const float* __restrict__ Wc,
    const float* __restrict__ bcv,
    const _Float16* __restrict__ ws,
    const int nsamp,
    float* __restrict__ out)
{
    const int wave = threadIdx.x >> 6;
    const int lane = threadIdx.x & 63;
    const int n    = blockIdx.x * WPB + wave; // one sample per wave

    __shared__ __align__(16) char s_raw[WPB * SLICE];

    if (n >= nsamp) return;                   // safe: no barriers anywhere

    const int t  = lane & 15;
    const int kq = lane >> 4;

    char* s_base = s_raw + wave * SLICE;      // private per-wave slice
    _Float16* s_PM = (_Float16*)(s_base);                 // P, then M
    _Float16* s_vt = (_Float16*)(s_base + OFF_VT);        // VT (one col-half)
    _Float16* s_gm = (_Float16*)(s_base + OFF_GM);
    _Float16* s_d  = (_Float16*)(s_base);                 // desc overlay (late)

    constexpr float LOG2E   = 1.44269504088896340736f;
    constexpr float TWO_PI  = 6.28318530717958647692f;
    constexpr float DLT     = TWO_PI / 16.0f;
    constexpr float INV_DLT = 16.0f / TWO_PI;
    constexpr float EPSF    = 1e-5f;

    const float st = sig_th[0];
    const float Kt = -LOG2E / (st * st + EPSF);
    const float sr = sig_rho[0];
    const float Kr = -LOG2E / (sr * sr + EPSF);
    float mr[NRH];
    #pragma unroll
    for (int r = 0; r < NRH; ++r) mr[r] = mu_rho[r * 16];

    // ---- zero P incl. pads (425 int4, 64 lanes -> 7 rounds) ----
    #pragma unroll
    for (int x = 0; x < 7; ++x) {
        const int idx = x * 64 + lane;
        if (idx < 425) ((int4*)s_PM)[idx] = make_int4(0, 0, 0, 0);
    }
    LDS_ORDER();                                  // [1] zero before compaction

    // ---- compaction: both rounds' global loads issued up front (R11) ----
    float mvh[2], thh[2], rhh[2];
    float4 f4h[2];
    #pragma unroll
    for (int h = 0; h < 2; ++h) {
        const int v = h * 64 + lane;
        mvh[h] = mask_g[n * NVERT + v];
        thh[h] = th_c[n * NVERT + v];
        rhh[h] = rho_c[n * NVERT + v];
        f4h[h] = *(const float4*)&feat_g[(n * NVERT + v) * 4];
    }
    int nc = 0;
    #pragma unroll
    for (int h = 0; h < 2; ++h) {
        const float mv   = mvh[h];
        const float thv  = thh[h];
        const float rhov = rhh[h];
        const float4 f4  = f4h[h];
        const bool act = (mv != 0.0f);
        const unsigned long long bal = __ballot(act);
        if (act) {
            const int pos = nc + (int)__popcll(bal & ((1ull << lane) - 1ull));
            int aa = (int)floorf(thv * INV_DLT);
            aa = aa > 15 ? 15 : (aa < 0 ? 0 : aa);
            const float rvp = thv - (float)aa * DLT - 0.5f * DLT;   // [-DLT/2, DLT/2)
            float R[NRH];
            #pragma unroll
            for (int r = 0; r < NRH; ++r) {
                const float dr = rhov - mr[r];
                R[r] = mv * exp2f(Kr * dr * dr);
            }
            const float fv[4] = {f4.x, f4.y, f4.z, f4.w};
            #pragma unroll
            for (int f = 0; f < 4; ++f) {
                #pragma unroll
                for (int r = 0; r < 4; ++r)
                    s_PM[(f * 4 + r) * PSTR + pos] = (_Float16)(fv[f] * R[r]);
                s_PM[(16 + f) * PSTR + pos] = (_Float16)(fv[f] * R[4]);
            }
            #pragma unroll
            for (int r = 0; r < NRH; ++r)
                s_PM[(20 + r) * PSTR + pos] = (_Float16)R[r];
            s_PM[(pos >> 3) * PSTR + 128 + (pos & 7)] = (_Float16)(rvp * (2.0f * INV_DLT));
            ((char*)s_PM)[(16 + (pos >> 4)) * 2 * PSTR + 256 + (pos & 15)] = (char)aa;
            s_gm[pos] = (_Float16)exp2f(Kt * rvp * rvp);
        }
        nc += (int)__popcll(bal);
    }
    LDS_DRAIN();                                  // [2] P/gm/tails complete

    // ---- chain 1: whole M (both tiles), software-pipelined chunks (R7).
    //      Preload chunk 0's A-frags + vert data; inside chunk ch, prefetch
    //      chunk ch+1 (P region immutable during chain1 -> safe to hoist). ----
    f32x4 M0[6], M1[6];
    #pragma unroll
    for (int cb = 0; cb < 6; ++cb) {
        M0[cb] = (f32x4){0.f, 0.f, 0.f, 0.f};
        M1[cb] = (f32x4){0.f, 0.f, 0.f, 0.f};
    }
    const int nch = (nc + 31) >> 5;
    const int cl = lane >> 1;
    const int dh = (lane & 1) * 3;
    // preload chunk 0
    half8 av0 = *(const half8*)(s_PM + t * PSTR + kq * 8);
    half8 av1 = *(const half8*)(s_PM + (16 + t) * PSTR + kq * 8);
    int   va  = (int)((char*)s_PM)[(16 + (cl >> 4)) * 2 * PSTR + 256 + (cl & 15)];
    float vu  = (float)s_PM[(cl >> 3) * PSTR + 128 + (cl & 7)];
    float vg  = (float)s_gm[cl];
    #pragma unroll 1
    for (int ch = 0; ch < nch; ++ch) {
        const bool valid = (ch * 32 + cl) < nc;
        float p0, p1, p2;
        if (dh == 0) { p0 = 1.0f; p1 = vu; p2 = vu * vu; }
        else { const float u2 = vu * vu; p0 = u2 * vu; p1 = u2 * u2; p2 = p0 * u2; }
        const _Float16 w0 = (_Float16)(vg * p0);
        const _Float16 w1 = (_Float16)(vg * p1);
        const _Float16 w2 = (_Float16)(vg * p2);
        const int ah  = va >> 3;                 // col-half this vert belongs to
        const int bi0 = ((va & 7) * NDEG + dh) * VSTR + cl;
        // prefetch chunk ch+1 (clamped; garbage beyond nc is masked next iter)
        const int chn = (ch + 1 < nch) ? (ch + 1) : ch;
        const int cgn = chn * 32 + cl;
        const half8 av0n = *(const half8*)(s_PM + t * PSTR + chn * 32 + kq * 8);
        const half8 av1n = *(const half8*)(s_PM + (16 + t) * PSTR + chn * 32 + kq * 8);
        const int   van  = (int)((char*)s_PM)[(16 + (cgn >> 4)) * 2 * PSTR + 256 + (cgn & 15)];
        const float vun  = (float)s_PM[(cgn >> 3) * PSTR + 128 + (cgn & 7)];
        const float vgn  = (float)s_gm[cgn];
        #pragma unroll
        for (int chalf = 0; chalf < 2; ++chalf) {
            LDS_ORDER();                  // prev col-half's VT reads before re-zero
            #pragma unroll
            for (int x = 0; x < 3; ++x)
                ((int4*)s_vt)[x * 64 + lane] = make_int4(0, 0, 0, 0);
            LDS_ORDER();                  // zero before scatter-build
            if (valid && ah == chalf) {
                s_vt[bi0]            = w0;
                s_vt[bi0 + VSTR]     = w1;
                s_vt[bi0 + 2 * VSTR] = w2;
            }
            LDS_ORDER();                  // build before fragment reads
            // tile1 t>8 reads rows 25..31 (in-slice garbage -> unread M rows)
            #pragma unroll
            for (int lct = 0; lct < 3; ++lct) {
                const half8 b = *(const half8*)(s_vt + (lct * 16 + t) * VSTR + kq * 8);
                __builtin_amdgcn_s_setprio(1);
                M0[chalf * 3 + lct] = __builtin_amdgcn_mfma_f32_16x16x32_f16(av0, b, M0[chalf * 3 + lct], 0, 0, 0);
                M1[chalf * 3 + lct] = __builtin_amdgcn_mfma_f32_16x16x32_f16(av1, b, M1[chalf * 3 + lct], 0, 0, 0);
                __builtin_amdgcn_s_setprio(0);
            }
        }
        av0 = av0n; av1 = av1n; va = van; vu = vun; vg = vgn;
    }
    LDS_ORDER();                                  // chain1 reads before M overwrite

    // ---- M (both tiles) -> LDS f16 A-layout. D: col=t, row=kq*4+reg ----
    #pragma unroll
    for (int cb = 0; cb < 6; ++cb) {
        const int md = cb * 16 + t;
        #pragma unroll
        for (int reg = 0; reg < 4; ++reg) {
            const int lr = kq * 4 + reg;
            s_PM[lr * PSTR + md] = (_Float16)M0[cb][reg];
            if (lr < 9)
                s_PM[(16 + lr) * PSTR + md] = (_Float16)M1[cb][reg];
        }
    }
    LDS_DRAIN();                                  // [3] M complete before A-frag reads

    // ---- chain2 A-frags -> regs (before desc overlays P/M) ----
    half8 A0[3], A1[3];
    #pragma unroll
    for (int ks = 0; ks < 3; ++ks) {
        A0[ks] = *(const half8*)(s_PM + t * PSTR + ks * 32 + kq * 8);
        A1[ks] = *(const half8*)(s_PM + (16 + t) * PSTR + ks * 32 + kq * 8);
    }
    LDS_ORDER();                                  // [4] A-frag reads before desc overlay

    // ---- chain 2: per g, BATCH all 12 B-frags -> regs, MFMA cluster,
    //      then epilogue with f16-packed den broadcast (R11). ----
    const half8* wsv = (const half8*)ws;
    #pragma unroll 1
    for (int g = 0; g < 4; ++g) {
        half8 B0[4], B1[4], B2[4];
        #pragma unroll
        for (int j = 0; j < 4; ++j) {
            const int nt = g * 4 + j;
            if (USEWS) {
                B0[j] = wsv[(size_t)((nt * 3 + 0) * 64 + lane)];
                B1[j] = wsv[(size_t)((nt * 3 + 1) * 64 + lane)];
                B2[j] = wsv[(size_t)((nt * 3 + 2) * 64 + lane)];
            } else {
                #pragma unroll
                for (int ks = 0; ks < 3; ++ks) {
                    half8 bb;
                    #pragma unroll
                    for (int jj = 0; jj < 8; ++jj) {
                        const int k = ks * 32 + kq * 8 + jj;
                        const int a = k / NDEG, d = k % NDEG;
                        const int mm = ((a + nt) & 15) - t;
                        const float s = fmaf((float)mm, DLT, 0.5f * DLT);
                        const float z = 2.0f * 0.69314718055994530942f * Kt * s * (0.5f * DLT);
                        float val = exp2f(Kt * s * s);
                        for (int dd = 1; dd <= d; ++dd) val *= z / (float)dd;
                        bb[jj] = (_Float16)val;
                    }
                    if (ks == 0) B0[j] = bb; else if (ks == 1) B1[j] = bb; else B2[j] = bb;
                }
            }
        }
        f32x4 C0g[4], C1g[4];
        #pragma unroll
        for (int j = 0; j < 4; ++j) {
            C0g[j] = (f32x4){0.f, 0.f, 0.f, 0.f};
            C1g[j] = (f32x4){0.f, 0.f, 0.f, 0.f};
        }
        #pragma unroll
        for (int j = 0; j < 4; ++j) {
            __builtin_amdgcn_s_setprio(1);
            C0g[j] = __builtin_amdgcn_mfma_f32_16x16x32_f16(A0[0], B0[j], C0g[j], 0, 0, 0);
            C1g[j] = __builtin_amdgcn_mfma_f32_16x16x32_f16(A1[0], B0[j], C1g[j], 0, 0, 0);
            C0g[j] = __builtin_amdgcn_mfma_f32_16x16x32_f16(A0[1], B1[j], C0g[j], 0, 0, 0);
            C1g[j] = __builtin_amdgcn_mfma_f32_16x16x32_f16(A1[1], B1[j], C1g[j], 0, 0, 0);
            C0g[j] = __builtin_amdgcn_mfma_f32_16x16x32_f16(A0[2], B2[j], C0g[j], 0, 0, 0);
            C1g[j] = __builtin_amdgcn_mfma_f32_16x16x32_f16(A1[2], B2[j], C1g[j], 0, 0, 0);
            __builtin_amdgcn_s_setprio(0);
        }
        // ---- epilogue: den[0..3] packed to 2 f16 pairs -> 3 bpermutes per
        //      (g,j) instead of 5; all 12 issued as one batch. den f16
        //      rounding adds <=2^-11 rel to desc (f16-bound downstream). ----
        unsigned g01[4], g23[4];
        float d4[4];
        {
            unsigned pk01[4], pk23[4];
            #pragma unroll
            for (int j = 0; j < 4; ++j) {
                union { _Float16 h[2]; unsigned u; } p, q;
                p.h[0] = (_Float16)C1g[j][0]; p.h[1] = (_Float16)C1g[j][1];
                q.h[0] = (_Float16)C1g[j][2]; q.h[1] = (_Float16)C1g[j][3];
                pk01[j] = p.u; pk23[j] = q.u;
            }
            #pragma unroll
            for (int j = 0; j < 4; ++j) {
                g01[j] = (unsigned)__shfl((int)pk01[j], 16 + t);
                g23[j] = (unsigned)__shfl((int)pk23[j], 16 + t);
                d4[j]  = __shfl(C1g[j][0], 32 + t);
            }
        }
        #pragma unroll
        for (int j = 0; j < 4; ++j) {
            const int nt = g * 4 + j;
            union { unsigned u; _Float16 h[2]; } u01, u23;
            u01.u = g01[j]; u23.u = g23[j];
            float den[5], inv[5];
            den[0] = (float)u01.h[0]; den[1] = (float)u01.h[1];
            den[2] = (float)u23.h[0]; den[3] = (float)u23.h[1];
            den[4] = d4[j];
            #pragma unroll
            for (int r = 0; r < NRH; ++r)
                inv[r] = __builtin_amdgcn_rcpf(den[r] + EPSF);
            #pragma unroll
            for (int reg = 0; reg < 4; ++reg)
                s_d[kq * DI + nt * DSTR + reg * 16 + t] =
                    (_Float16)(C0g[j][reg] * inv[reg]);
            if (kq == 0) {
                #pragma unroll
                for (int reg = 0; reg < 4; ++reg)
                    s_d[reg * DI + nt * DSTR + 64 + t] =
                        (_Float16)(C1g[j][reg] * inv[4]);
            }
        }
    }
    LDS_DRAIN();                                  // [5] desc complete before phase2 reads

    // ---- phase 2: per i, BATCH 3 desc A-frags + all 15 W-frags, then
    //      MFMA cluster. unroll 1 keeps VGPR <= 128. ----
    #pragma unroll 1
    for (int i = 0; i < 4; ++i) {
        half8 a[3];
        #pragma unroll
        for (int ks = 0; ks < 3; ++ks)
            a[ks] = *(const half8*)(s_d + i * DI + t * DSTR + ks * 32 + kq * 8);
        half8 b[15];
        #pragma unroll
        for (int ks = 0; ks < 3; ++ks) {
            #pragma unroll
            for (int tl = 0; tl < 5; ++tl) {
                if (USEWS) {
                    b[ks * 5 + tl] = wsv[(size_t)((NSET_C + (i * 5 + tl) * 3 + ks) * 64 + lane)];
                } else {
                    const int cc  = tl * 16 + t;
                    const int bb0 = ks * 32 + kq * 8;
                    #pragma unroll
                    for (int j = 0; j < 8; ++j) {
                        const int bb = bb0 + j;
                        b[ks * 5 + tl][j] = (_Float16)((bb < NBINS) ? Wc[i * NBINS * NBINS + bb * NBINS + cc] : 0.0f);
                    }
                }
            }
        }
        f32x4 Cc[5];
        #pragma unroll
        for (int tl = 0; tl < 5; ++tl) Cc[tl] = (f32x4){0.f, 0.f, 0.f, 0.f};
        __builtin_amdgcn_s_setprio(1);
        #pragma unroll
        for (int ks = 0; ks < 3; ++ks) {
            #pragma unroll
            for (int tl = 0; tl < 5; ++tl)
                Cc[tl] = __builtin_amdgcn_mfma_f32_16x16x32_f16(a[ks], b[ks * 5 + tl], Cc[tl], 0, 0, 0);
        }
        __builtin_amdgcn_s_setprio(0);
        #pragma unroll
        for (int tl = 0; tl < 5; ++tl) {
            float mx = fmaxf(fmaxf(Cc[tl][0], Cc[tl][1]), fmaxf(Cc[tl][2], Cc[tl][3]));
            mx = fmaxf(mx, __shfl_xor(mx, 16));
            mx = fmaxf(mx, __shfl_xor(mx, 32));
            if (lane < 16) {
                const int cc = tl * 16 + lane;
                out[(size_t)n * 320 + i * NBINS + cc] =
                    fmaxf(mx + bcv[i * NBINS + cc], 0.0f);
            }
        }
    }
}

extern "C" void kernel_launch(void* const* d_in, const int* in_sizes, int n_in,
                              void* d_out, int out_size, void* d_ws, size_t ws_size,
                              hipStream_t stream) {
    const float* rho   = (const float*)d_in[0];
    const float* theta = (const float*)d_in[1];
    const float* feat  = (const float*)d_in[2];
    const float* mask  = (const float*)d_in[3];
    const float* mu_r  = (const float*)d_in[4];
    const float* sg_r  = (const float*)d_in[5];
    const float* mu_t  = (const float*)d_in[6];
    const float* sg_t  = (const float*)d_in[7];
    const float* W     = (const float*)d_in[8];
    const float* bconv = (const float*)d_in[9];
    float* outp = (float*)d_out;

    const int nsamp = in_sizes[0] / NVERT;
    const int ngrid = (nsamp + WPB - 1) / WPB;    // 4 samples per WG
    const int useWs = (ws_size >= (size_t)WS_BYTES) ? 1 : 0;
    _Float16* wsh = (_Float16*)d_ws;

    if (useWs) {
        prep_frags<<<NSET_C + NSET_W, 64, 0, stream>>>(W, sg_t, wsh);
        masif_geo_conv<1><<<ngrid, 64 * WPB, 0, stream>>>(
            rho, theta, feat, mask, mu_r, sg_r, mu_t, sg_t, W, bconv,
            wsh, nsamp, outp);
    } else {
        masif_geo_conv<0><<<ngrid, 64 * WPB, 0, stream>>>(
            rho, theta, feat, mask, mu_r, sg_r, mu_t, sg_t, W, bconv,
            wsh, nsamp, outp);
    }
}

// Round 13
// 106.253 us; speedup vs baseline: 1.1113x; 1.0173x over previous
//
#include <hip/hip_runtime.h>
#include <math.h>

#define NBINS 80
#define NVERT 128
#define NRH 5
#define NDEG 6           // Taylor terms d=0..5; remainder ~1e-5 (<< f16 eps)

#define PSTR 136         // halves per P/M row; cols 0..127 data, 128..135 pad
#define VSTR 32          // halves per VT row
#define DSTR 80          // halves per desc row (per nt)
#define DI   1280        // halves per desc feature slab (desc = exactly 10240 B)

#define OFF_VT 6800      // P/M: 25*136*2 = 6800 B at [0,6800)
#define VTSZ   3072      // VT: 48 rows x 32 halves (one a-half at a time)
#define OFF_GM 9872      // gm f16 x 128 = 256 B at [9872,10128)
#define SLICE  10240     // per-sample LDS slice; desc overlay [0,10240) after chain1
#define WPB    4         // samples (waves) per WG; 4*10240 = 40960 B/WG
                         // -> 4 WGs/CU = 16 waves/CU (LDS-capped maximum:
                         // desc 10240 B/sample is irreducible)

#define NSET_C 48        // C-matrix frag sets: 16 nt x 3 ks
#define NSET_W 60        // W frag sets: 4 i x 5 tiles x 3 ks
#define WS_BYTES ((NSET_C + NSET_W) * 64 * 8 * 2)

// Same-wave LDS ordering fences (replace __syncthreads; R3 lesson):
#define LDS_ORDER() asm volatile("" ::: "memory")
#define LDS_DRAIN() asm volatile("s_waitcnt lgkmcnt(0)" ::: "memory")

typedef _Float16 half8 __attribute__((ext_vector_type(8)));
typedef float f32x4 __attribute__((ext_vector_type(4)));

// ---- prep: constant C-matrix frags + W frags in d_ws (unchanged, verified) ----
__global__ __launch_bounds__(64) void prep_frags(const float* __restrict__ Wc,
                                                 const float* __restrict__ sig_th,
                                                 _Float16* __restrict__ ws) {
    const int blk  = blockIdx.x;
    const int lane = threadIdx.x;
    constexpr float TWO_PI = 6.28318530717958647692f;
    constexpr float DLT    = TWO_PI / 16.0f;
    constexpr float LN2    = 0.69314718055994530942f;
    half8 h;
    if (blk < NSET_C) {
        constexpr float LOG2E = 1.44269504088896340736f;
        constexpr float EPSF  = 1e-5f;
        const float st = sig_th[0];
        const float Kt = -LOG2E / (st * st + EPSF);
        const int ks = blk % 3;
        const int nt = blk / 3;
        const int t  = lane & 15;
        const int q  = lane >> 4;
        #pragma unroll
        for (int j = 0; j < 8; ++j) {
            const int k = ks * 32 + q * 8 + j;     // 0..95
            const int a = k / NDEG;
            const int d = k % NDEG;
            const int m = ((a + nt) & 15) - t;
            const float s = fmaf((float)m, DLT, 0.5f * DLT);
            const float z = 2.0f * LN2 * Kt * s * (0.5f * DLT);
            float val = exp2f(Kt * s * s);
            for (int dd = 1; dd <= d; ++dd) val *= z / (float)dd;
            h[j] = (_Float16)val;
        }
    } else {
        const int e    = blk - NSET_C;
        const int ks   = e % 3;
        const int tile = (e / 3) % 5;
        const int i    = e / 15;
        const int cc   = tile * 16 + (lane & 15);
        const int bb0  = ks * 32 + (lane >> 4) * 8;
        #pragma unroll
        for (int j = 0; j < 8; ++j) {
            const int bb = bb0 + j;
            h[j] = (_Float16)((bb < NBINS) ? Wc[i * NBINS * NBINS + bb * NBINS + cc] : 0.0f);
        }
    }
    *(half8*)(ws + ((size_t)blk * 64 + lane) * 8) = h;
}

// WAVE-PER-SAMPLE, 4 samples per 256-thread WG (R12 base = session best;
// R13 DS-tail trims). ZERO barriers; same-wave DS ordering via LDS_ORDER/
// LDS_DRAIN (R3 lesson). R13 vs R12: (1) epilogue d4 broadcast packs
// C1g[j][0] j-pairs as f16x2 -> 2 shfls/g instead of 4; (2) phase2 final
// max-reduce packs tl0..3 partial maxes as two f16 pairs reduced with
// v_pk_max_f16 -> 6 shfls/i instead of 10 (max is monotone, so
// round(max)=max(round); f16 2^-11 rel << 0.046 threshold).
template <int USEWS>
__global__ __launch_bounds__(256, 4) void masif_geo_conv(
    const float* __restrict__ rho_c,
    const float* __restrict__ th_c,
    const float* __restrict__ feat_g,
    const float* __restrict__ mask_g,
    const float* __restrict__ mu_rho,
    const float* __restrict__ sig_rho,
    const float* __restrict__ mu_th,
    const float* __restrict__ sig_th,
    const float* __restrict__ Wc,
    const float* __restrict__ bcv,
    const _Float16* __restrict__ ws,
    const int nsamp,
    float* __restrict__ out)
{
    const int wave = threadIdx.x >> 6;
    const int lane = threadIdx.x & 63;
    const int n    = blockIdx.x * WPB + wave; // one sample per wave

    __shared__ __align__(16) char s_raw[WPB * SLICE];

    if (n >= nsamp) return;                   // safe: no barriers anywhere

    const int t  = lane & 15;
    const int kq = lane >> 4;

    char* s_base = s_raw + wave * SLICE;      // private per-wave slice
    _Float16* s_PM = (_Float16*)(s_base);                 // P, then M
    _Float16* s_vt = (_Float16*)(s_base + OFF_VT);        // VT (one col-half)
    _Float16* s_gm = (_Float16*)(s_base + OFF_GM);
    _Float16* s_d  = (_Float16*)(s_base);                 // desc overlay (late)

    constexpr float LOG2E   = 1.44269504088896340736f;
    constexpr float TWO_PI  = 6.28318530717958647692f;
    constexpr float DLT     = TWO_PI / 16.0f;
    constexpr float INV_DLT = 16.0f / TWO_PI;
    constexpr float EPSF    = 1e-5f;

    const float st = sig_th[0];
    const float Kt = -LOG2E / (st * st + EPSF);
    const float sr = sig_rho[0];
    const float Kr = -LOG2E / (sr * sr + EPSF);
    float mr[NRH];
    #pragma unroll
    for (int r = 0; r < NRH; ++r) mr[r] = mu_rho[r * 16];

    // ---- zero P incl. pads (425 int4, 64 lanes -> 7 rounds) ----
    #pragma unroll
    for (int x = 0; x < 7; ++x) {
        const int idx = x * 64 + lane;
        if (idx < 425) ((int4*)s_PM)[idx] = make_int4(0, 0, 0, 0);
    }
    LDS_ORDER();                                  // [1] zero before compaction

    // ---- compaction: both rounds' global loads issued up front (R11) ----
    float mvh[2], thh[2], rhh[2];
    float4 f4h[2];
    #pragma unroll
    for (int h = 0; h < 2; ++h) {
        const int v = h * 64 + lane;
        mvh[h] = mask_g[n * NVERT + v];
        thh[h] = th_c[n * NVERT + v];
        rhh[h] = rho_c[n * NVERT + v];
        f4h[h] = *(const float4*)&feat_g[(n * NVERT + v) * 4];
    }
    int nc = 0;
    #pragma unroll
    for (int h = 0; h < 2; ++h) {
        const float mv   = mvh[h];
        const float thv  = thh[h];
        const float rhov = rhh[h];
        const float4 f4  = f4h[h];
        const bool act = (mv != 0.0f);
        const unsigned long long bal = __ballot(act);
        if (act) {
            const int pos = nc + (int)__popcll(bal & ((1ull << lane) - 1ull));
            int aa = (int)floorf(thv * INV_DLT);
            aa = aa > 15 ? 15 : (aa < 0 ? 0 : aa);
            const float rvp = thv - (float)aa * DLT - 0.5f * DLT;   // [-DLT/2, DLT/2)
            float R[NRH];
            #pragma unroll
            for (int r = 0; r < NRH; ++r) {
                const float dr = rhov - mr[r];
                R[r] = mv * exp2f(Kr * dr * dr);
            }
            const float fv[4] = {f4.x, f4.y, f4.z, f4.w};
            #pragma unroll
            for (int f = 0; f < 4; ++f) {
                #pragma unroll
                for (int r = 0; r < 4; ++r)
                    s_PM[(f * 4 + r) * PSTR + pos] = (_Float16)(fv[f] * R[r]);
                s_PM[(16 + f) * PSTR + pos] = (_Float16)(fv[f] * R[4]);
            }
            #pragma unroll
            for (int r = 0; r < NRH; ++r)
                s_PM[(20 + r) * PSTR + pos] = (_Float16)R[r];
            s_PM[(pos >> 3) * PSTR + 128 + (pos & 7)] = (_Float16)(rvp * (2.0f * INV_DLT));
            ((char*)s_PM)[(16 + (pos >> 4)) * 2 * PSTR + 256 + (pos & 15)] = (char)aa;
            s_gm[pos] = (_Float16)exp2f(Kt * rvp * rvp);
        }
        nc += (int)__popcll(bal);
    }
    LDS_DRAIN();                                  // [2] P/gm/tails complete

    // ---- chain 1: whole M (both tiles), software-pipelined chunks (R7).
    //      Preload chunk 0's A-frags + vert data; inside chunk ch, prefetch
    //      chunk ch+1 (P region immutable during chain1 -> safe to hoist). ----
    f32x4 M0[6], M1[6];
    #pragma unroll
    for (int cb = 0; cb < 6; ++cb) {
        M0[cb] = (f32x4){0.f, 0.f, 0.f, 0.f};
        M1[cb] = (f32x4){0.f, 0.f, 0.f, 0.f};
    }
    const int nch = (nc + 31) >> 5;
    const int cl = lane >> 1;
    const int dh = (lane & 1) * 3;
    // preload chunk 0
    half8 av0 = *(const half8*)(s_PM + t * PSTR + kq * 8);
    half8 av1 = *(const half8*)(s_PM + (16 + t) * PSTR + kq * 8);
    int   va  = (int)((char*)s_PM)[(16 + (cl >> 4)) * 2 * PSTR + 256 + (cl & 15)];
    float vu  = (float)s_PM[(cl >> 3) * PSTR + 128 + (cl & 7)];
    float vg  = (float)s_gm[cl];
    #pragma unroll 1
    for (int ch = 0; ch < nch; ++ch) {
        const bool valid = (ch * 32 + cl) < nc;
        float p0, p1, p2;
        if (dh == 0) { p0 = 1.0f; p1 = vu; p2 = vu * vu; }
        else { const float u2 = vu * vu; p0 = u2 * vu; p1 = u2 * u2; p2 = p0 * u2; }
        const _Float16 w0 = (_Float16)(vg * p0);
        const _Float16 w1 = (_Float16)(vg * p1);
        const _Float16 w2 = (_Float16)(vg * p2);
        const int ah  = va >> 3;                 // col-half this vert belongs to
        const int bi0 = ((va & 7) * NDEG + dh) * VSTR + cl;
        // prefetch chunk ch+1 (clamped; garbage beyond nc is masked next iter)
        const int chn = (ch + 1 < nch) ? (ch + 1) : ch;
        const int cgn = chn * 32 + cl;
        const half8 av0n = *(const half8*)(s_PM + t * PSTR + chn * 32 + kq * 8);
        const half8 av1n = *(const half8*)(s_PM + (16 + t) * PSTR + chn * 32 + kq * 8);
        const int   van  = (int)((char*)s_PM)[(16 + (cgn >> 4)) * 2 * PSTR + 256 + (cgn & 15)];
        const float vun  = (float)s_PM[(cgn >> 3) * PSTR + 128 + (cgn & 7)];
        const float vgn  = (float)s_gm[cgn];
        #pragma unroll
        for (int chalf = 0; chalf < 2; ++chalf) {
            LDS_ORDER();                  // prev col-half's VT reads before re-zero
            #pragma unroll
            for (int x = 0; x < 3; ++x)
                ((int4*)s_vt)[x * 64 + lane] = make_int4(0, 0, 0, 0);
            LDS_ORDER();                  // zero before scatter-build
            if (valid && ah == chalf) {
                s_vt[bi0]            = w0;
                s_vt[bi0 + VSTR]     = w1;
                s_vt[bi0 + 2 * VSTR] = w2;
            }
            LDS_ORDER();                  // build before fragment reads
            // tile1 t>8 reads rows 25..31 (in-slice garbage -> unread M rows)
            #pragma unroll
            for (int lct = 0; lct < 3; ++lct) {
                const half8 b = *(const half8*)(s_vt + (lct * 16 + t) * VSTR + kq * 8);
                __builtin_amdgcn_s_setprio(1);
                M0[chalf * 3 + lct] = __builtin_amdgcn_mfma_f32_16x16x32_f16(av0, b, M0[chalf * 3 + lct], 0, 0, 0);
                M1[chalf * 3 + lct] = __builtin_amdgcn_mfma_f32_16x16x32_f16(av1, b, M1[chalf * 3 + lct], 0, 0, 0);
                __builtin_amdgcn_s_setprio(0);
            }
        }
        av0 = av0n; av1 = av1n; va = van; vu = vun; vg = vgn;
    }
    LDS_ORDER();                                  // chain1 reads before M overwrite

    // ---- M (both tiles) -> LDS f16 A-layout. D: col=t, row=kq*4+reg ----
    #pragma unroll
    for (int cb = 0; cb < 6; ++cb) {
        const int md = cb * 16 + t;
        #pragma unroll
        for (int reg = 0; reg < 4; ++reg) {
            const int lr = kq * 4 + reg;
            s_PM[lr * PSTR + md] = (_Float16)M0[cb][reg];
            if (lr < 9)
                s_PM[(16 + lr) * PSTR + md] = (_Float16)M1[cb][reg];
        }
    }
    LDS_DRAIN();                                  // [3] M complete before A-frag reads

    // ---- chain2 A-frags -> regs (before desc overlays P/M) ----
    half8 A0[3], A1[3];
    #pragma unroll
    for (int ks = 0; ks < 3; ++ks) {
        A0[ks] = *(const half8*)(s_PM + t * PSTR + ks * 32 + kq * 8);
        A1[ks] = *(const half8*)(s_PM + (16 + t) * PSTR + ks * 32 + kq * 8);
    }
    LDS_ORDER();                                  // [4] A-frag reads before desc overlay

    // ---- chain 2: per g, BATCH all 12 B-frags -> regs, MFMA cluster,
    //      then epilogue with fully f16-packed den broadcast (R11+R13). ----
    const half8* wsv = (const half8*)ws;
    #pragma unroll 1
    for (int g = 0; g < 4; ++g) {
        half8 B0[4], B1[4], B2[4];
        #pragma unroll
        for (int j = 0; j < 4; ++j) {
            const int nt = g * 4 + j;
            if (USEWS) {
                B0[j] = wsv[(size_t)((nt * 3 + 0) * 64 + lane)];
                B1[j] = wsv[(size_t)((nt * 3 + 1) * 64 + lane)];
                B2[j] = wsv[(size_t)((nt * 3 + 2) * 64 + lane)];
            } else {
                #pragma unroll
                for (int ks = 0; ks < 3; ++ks) {
                    half8 bb;
                    #pragma unroll
                    for (int jj = 0; jj < 8; ++jj) {
                        const int k = ks * 32 + kq * 8 + jj;
                        const int a = k / NDEG, d = k % NDEG;
                        const int mm = ((a + nt) & 15) - t;
                        const float s = fmaf((float)mm, DLT, 0.5f * DLT);
                        const float z = 2.0f * 0.69314718055994530942f * Kt * s * (0.5f * DLT);
                        float val = exp2f(Kt * s * s);
                        for (int dd = 1; dd <= d; ++dd) val *= z / (float)dd;
                        bb[jj] = (_Float16)val;
                    }
                    if (ks == 0) B0[j] = bb; else if (ks == 1) B1[j] = bb; else B2[j] = bb;
                }
            }
        }
        f32x4 C0g[4], C1g[4];
        #pragma unroll
        for (int j = 0; j < 4; ++j) {
            C0g[j] = (f32x4){0.f, 0.f, 0.f, 0.f};
            C1g[j] = (f32x4){0.f, 0.f, 0.f, 0.f};
        }
        #pragma unroll
        for (int j = 0; j < 4; ++j) {
            __builtin_amdgcn_s_setprio(1);
            C0g[j] = __builtin_amdgcn_mfma_f32_16x16x32_f16(A0[0], B0[j], C0g[j], 0, 0, 0);
            C1g[j] = __builtin_amdgcn_mfma_f32_16x16x32_f16(A1[0], B0[j], C1g[j], 0, 0, 0);
            C0g[j] = __builtin_amdgcn_mfma_f32_16x16x32_f16(A0[1], B1[j], C0g[j], 0, 0, 0);
            C1g[j] = __builtin_amdgcn_mfma_f32_16x16x32_f16(A1[1], B1[j], C1g[j], 0, 0, 0);
            C0g[j] = __builtin_amdgcn_mfma_f32_16x16x32_f16(A0[2], B2[j], C0g[j], 0, 0, 0);
            C1g[j] = __builtin_amdgcn_mfma_f32_16x16x32_f16(A1[2], B2[j], C1g[j], 0, 0, 0);
            __builtin_amdgcn_s_setprio(0);
        }
        // ---- epilogue: den fully f16-packed -> 10 bpermutes per g
        //      (8 for den[0..3] pairs + 2 for den[4] j-pairs; was 12). ----
        unsigned g01[4], g23[4], d01, d23;
        {
            unsigned pk01[4], pk23[4];
            #pragma unroll
            for (int j = 0; j < 4; ++j) {
                union { _Float16 h[2]; unsigned u; } p, q;
                p.h[0] = (_Float16)C1g[j][0]; p.h[1] = (_Float16)C1g[j][1];
                q.h[0] = (_Float16)C1g[j][2]; q.h[1] = (_Float16)C1g[j][3];
                pk01[j] = p.u; pk23[j] = q.u;
            }
            union { _Float16 h[2]; unsigned u; } ra, rb;
            ra.h[0] = (_Float16)C1g[0][0]; ra.h[1] = (_Float16)C1g[1][0];
            rb.h[0] = (_Float16)C1g[2][0]; rb.h[1] = (_Float16)C1g[3][0];
            #pragma unroll
            for (int j = 0; j < 4; ++j) {
                g01[j] = (unsigned)__shfl((int)pk01[j], 16 + t);
                g23[j] = (unsigned)__shfl((int)pk23[j], 16 + t);
            }
            d01 = (unsigned)__shfl((int)ra.u, 32 + t);
            d23 = (unsigned)__shfl((int)rb.u, 32 + t);
        }
        #pragma unroll
        for (int j = 0; j < 4; ++j) {
            const int nt = g * 4 + j;
            union { unsigned u; _Float16 h[2]; } u01, u23, ud;
            u01.u = g01[j]; u23.u = g23[j];
            ud.u  = (j < 2) ? d01 : d23;
            float den[5], inv[5];
            den[0] = (float)u01.h[0]; den[1] = (float)u01.h[1];
            den[2] = (float)u23.h[0]; den[3] = (float)u23.h[1];
            den[4] = (float)ud.h[j & 1];
            #pragma unroll
            for (int r = 0; r < NRH; ++r)
                inv[r] = __builtin_amdgcn_rcpf(den[r] + EPSF);
            #pragma unroll
            for (int reg = 0; reg < 4; ++reg)
                s_d[kq * DI + nt * DSTR + reg * 16 + t] =
                    (_Float16)(C0g[j][reg] * inv[reg]);
            if (kq == 0) {
                #pragma unroll
                for (int reg = 0; reg < 4; ++reg)
                    s_d[reg * DI + nt * DSTR + 64 + t] =
                        (_Float16)(C1g[j][reg] * inv[4]);
            }
        }
    }
    LDS_DRAIN();                                  // [5] desc complete before phase2 reads

    // ---- phase 2: per i, BATCH 3 desc A-frags + all 15 W-frags, then
    //      MFMA cluster; f16-packed cross-lane max (R13: 6 shfls/i). ----
    #pragma unroll 1
    for (int i = 0; i < 4; ++i) {
        half8 a[3];
        #pragma unroll
        for (int ks = 0; ks < 3; ++ks)
            a[ks] = *(const half8*)(s_d + i * DI + t * DSTR + ks * 32 + kq * 8);
        half8 b[15];
        #pragma unroll
        for (int ks = 0; ks < 3; ++ks) {
            #pragma unroll
            for (int tl = 0; tl < 5; ++tl) {
                if (USEWS) {
                    b[ks * 5 + tl] = wsv[(size_t)((NSET_C + (i * 5 + tl) * 3 + ks) * 64 + lane)];
                } else {
                    const int cc  = tl * 16 + t;
                    const int bb0 = ks * 32 + kq * 8;
                    #pragma unroll
                    for (int j = 0; j < 8; ++j) {
                        const int bb = bb0 + j;
                        b[ks * 5 + tl][j] = (_Float16)((bb < NBINS) ? Wc[i * NBINS * NBINS + bb * NBINS + cc] : 0.0f);
                    }
                }
            }
        }
        f32x4 Cc[5];
        #pragma unroll
        for (int tl = 0; tl < 5; ++tl) Cc[tl] = (f32x4){0.f, 0.f, 0.f, 0.f};
        __builtin_amdgcn_s_setprio(1);
        #pragma unroll
        for (int ks = 0; ks < 3; ++ks) {
            #pragma unroll
            for (int tl = 0; tl < 5; ++tl)
                Cc[tl] = __builtin_amdgcn_mfma_f32_16x16x32_f16(a[ks], b[ks * 5 + tl], Cc[tl], 0, 0, 0);
        }
        __builtin_amdgcn_s_setprio(0);
        // per-lane partial maxes
        float pmx[5];
        #pragma unroll
        for (int tl = 0; tl < 5; ++tl)
            pmx[tl] = fmaxf(fmaxf(Cc[tl][0], Cc[tl][1]), fmaxf(Cc[tl][2], Cc[tl][3]));
        // packed cross-lane reduce: tl0..3 as two f16 pairs (v_pk_max_f16,
        // monotone so round(max)=max(round)), tl4 as f32.
        union { _Float16 h[2]; unsigned u; } a01, a23, o01, o23;
        a01.h[0] = (_Float16)pmx[0]; a01.h[1] = (_Float16)pmx[1];
        a23.h[0] = (_Float16)pmx[2]; a23.h[1] = (_Float16)pmx[3];
        float m4 = pmx[4];
        #pragma unroll
        for (int stg = 0; stg < 2; ++stg) {
            const int dlt = stg ? 32 : 16;
            o01.u = (unsigned)__shfl_xor((int)a01.u, dlt);
            o23.u = (unsigned)__shfl_xor((int)a23.u, dlt);
            asm("v_pk_max_f16 %0, %1, %2" : "=v"(a01.u) : "v"(a01.u), "v"(o01.u));
            asm("v_pk_max_f16 %0, %1, %2" : "=v"(a23.u) : "v"(a23.u), "v"(o23.u));
            m4 = fmaxf(m4, __shfl_xor(m4, dlt));
        }
        if (lane < 16) {
            const float mxv[5] = { (float)a01.h[0], (float)a01.h[1],
                                   (float)a23.h[0], (float)a23.h[1], m4 };
            #pragma unroll
            for (int tl = 0; tl < 5; ++tl) {
                const int cc = tl * 16 + lane;
                out[(size_t)n * 320 + i * NBINS + cc] =
                    fmaxf(mxv[tl] + bcv[i * NBINS + cc], 0.0f);
            }
        }
    }
}

extern "C" void kernel_launch(void* const* d_in, const int* in_sizes, int n_in,
                              void* d_out, int out_size, void* d_ws, size_t ws_size,
                              hipStream_t stream) {
    const float* rho   = (const float*)d_in[0];
    const float* theta = (const float*)d_in[1];
    const float* feat  = (const float*)d_in[2];
    const float* mask  = (const float*)d_in[3];
    const float* mu_r  = (const float*)d_in[4];
    const float* sg_r  = (const float*)d_in[5];
    const float* mu_t  = (const float*)d_in[6];
    const float* sg_t  = (const float*)d_in[7];
    const float* W     = (const float*)d_in[8];
    const float* bconv = (const float*)d_in[9];
    float* outp = (float*)d_out;

    const int nsamp = in_sizes[0] / NVERT;
    const int ngrid = (nsamp + WPB - 1) / WPB;    // 4 samples per WG
    const int useWs = (ws_size >= (size_t)WS_BYTES) ? 1 : 0;
    _Float16* wsh = (_Float16*)d_ws;

    if (useWs) {
        prep_frags<<<NSET_C + NSET_W, 64, 0, stream>>>(W, sg_t, wsh);
        masif_geo_conv<1><<<ngrid, 64 * WPB, 0, stream>>>(
            rho, theta, feat, mask, mu_r, sg_r, mu_t, sg_t, W, bconv,
            wsh, nsamp, outp);
    } else {
        masif_geo_conv<0><<<ngrid, 64 * WPB, 0, stream>>>(
            rho, theta, feat, mask, mu_r, sg_r, mu_t, sg_t, W, bconv,
            wsh, nsamp, outp);
    }
}